// Round 11
// baseline (35.624 us; speedup 1.0000x reference)
//
#include <hip/hip_runtime.h>
#include <math.h>

namespace {

constexpr float kAlpha   = 0.75f;
constexpr int   kNumNeg  = 10000;
constexpr int   kNumHard = 100;
constexpr int   kRatio   = 100;
constexpr int   kB       = 8;
constexpr int   kN       = 64 * 128 * 128;     // 1048576
constexpr int   kTpb     = 1024;
constexpr int   kWaves   = kTpb / 64;          // 16
constexpr int   kGatherPerB = 10;              // 10*1024 >= 10000
constexpr int   kStreamPerB = 64;
constexpr int   kPerB    = kGatherPerB + kStreamPerB;    // 74
constexpr int   kGatherBlocks = kB * kGatherPerB;        // 80
constexpr int   kGrid    = kGatherBlocks + kB * kStreamPerB;  // 592
constexpr int   kVPer    = (kNumNeg + kTpb - 1) / kTpb;  // 10
constexpr unsigned kSentinel = 0xFFFFFFFFu;

// workspace layout (word offsets)
constexpr int oPartials  = 0;       // 8*64*2 floats
constexpr int oBatchLoss = 1024;    // 8 floats
constexpr int oCnt       = 1040;    // 8 u32 per-batch arrival counters
constexpr int oGCnt      = 1048;    // 1 u32 global counter
constexpr int oGvals     = 1536;    // 80000 u32

__device__ __forceinline__ float loss_at(float pred, float target, float mask) {
    float prob = 1.0f / (1.0f + expf(-pred));
    prob = fminf(fmaxf(prob, 1.0e-4f), 1.0f - 1.0e-4f);
    bool pos = (target == 1.0f);
    float alpha_f = pos ? kAlpha : (1.0f - kAlpha);
    float pt = pos ? (1.0f - prob) : prob;
    float focal_w = alpha_f * pt * pt;
    float bce = fmaxf(pred, 0.0f) - pred * target + log1pf(expf(-fabsf(pred)));
    float loss = (mask == 0.0f) ? focal_w * bce : 0.0f;
    if (pos && prob < 0.8f) loss *= 4.0f;
    return loss;
}

// Relaxed device-scope accessors: coherent-point traffic, NO cache
// maintenance (the R5/R7 storms came from release/acquire wbL2/invL2).
__device__ __forceinline__ void cstore(unsigned* p, unsigned v) {
    __hip_atomic_store(p, v, __ATOMIC_RELAXED, __HIP_MEMORY_SCOPE_AGENT);
}
__device__ __forceinline__ unsigned cload(const unsigned* p) {
    return __hip_atomic_load(p, __ATOMIC_RELAXED, __HIP_MEMORY_SCOPE_AGENT);
}
__device__ __forceinline__ void cstoref(float* p, float v) {
    __hip_atomic_store(p, v, __ATOMIC_RELAXED, __HIP_MEMORY_SCOPE_AGENT);
}
__device__ __forceinline__ float cloadf(const float* p) {
    return __hip_atomic_load(p, __ATOMIC_RELAXED, __HIP_MEMORY_SCOPE_AGENT);
}

// One kernel. 512 stream blocks + 80 gather blocks; per batch, the LAST of
// its 74 producers (relaxed fetch_add after vmcnt(0)-drained write-through
// stores) runs the radix select inline. No spins, no fences, deadlock-free
// under any scheduling; elected block varies but computed value does not.
__global__ void __launch_bounds__(kTpb) fused_kernel(
        const float* __restrict__ pred, const float* __restrict__ target,
        const float* __restrict__ mask, const int* __restrict__ neg_idx,
        unsigned* __restrict__ ws, float* __restrict__ out) {
    const int blk = blockIdx.x;
    const int tid = threadIdx.x;
    const int wave = tid >> 6, lane = tid & 63;
    float* wsf = (float*)ws;

    __shared__ unsigned whist[2][kWaves][256];        // 32 KB (select)
    __shared__ float r0[kWaves], r1[kWaves], r2[kWaves], r3[kWaves];
    __shared__ float red[kWaves];
    __shared__ float sh_np, sh_ps;
    __shared__ unsigned sh_krem, sh_prefix;
    __shared__ int sh_done, sh_last;

    int b;
    if (blk < kGatherBlocks) {
        // ---- gather role ----
        b = blk / kGatherPerB;
        const int sub = blk % kGatherPerB;
        const int j = sub * kTpb + tid;
        if (j < kNumNeg) {
            const size_t base = (size_t)b * kN;
            const int gi = neg_idx[(size_t)b * kNumNeg + j];
            const float tg = target[base + gi];
            unsigned outv;
            if (tg == 1.0f) {
                outv = kSentinel;
            } else {
                float v = loss_at(pred[base + gi], tg, mask[base + gi]);
                outv = __float_as_uint(v);            // v >= 0, finite
            }
            cstore(&ws[oGvals + b * kNumNeg + j], outv);
        }
    } else {
        // ---- stream role: 4 independent float4 loads per thread ----
        const int s = blk - kGatherBlocks;
        b = s >> 6;
        const int slice = s & 63;
        const size_t base = (size_t)b * kN;
        const float4* t4 = (const float4*)(target + base);
        const int tb = slice * kTpb + tid;            // [0, 65536)
        constexpr int kStride = kStreamPerB * kTpb;   // 65536; nvec = 4*kStride
        float4 v0 = t4[tb];
        float4 v1 = t4[tb + kStride];
        float4 v2 = t4[tb + 2 * kStride];
        float4 v3 = t4[tb + 3 * kStride];

        float cnt = 0.0f, psum = 0.0f;
        const float4 vv[4] = {v0, v1, v2, v3};
        #pragma unroll
        for (int it = 0; it < 4; ++it) {
            const int i = tb + it * kStride;
            float tvv[4] = {vv[it].x, vv[it].y, vv[it].z, vv[it].w};
            #pragma unroll
            for (int c = 0; c < 4; ++c) {
                if (tvv[c] == 1.0f) {
                    int gi = i * 4 + c;
                    cnt += 1.0f;
                    psum += loss_at(pred[base + gi], 1.0f, mask[base + gi]);
                }
            }
        }
        #pragma unroll
        for (int off = 32; off > 0; off >>= 1) {
            cnt  += __shfl_down(cnt, off);
            psum += __shfl_down(psum, off);
        }
        if (lane == 0) { r0[wave] = cnt; r1[wave] = psum; }
        __syncthreads();
        if (tid == 0) {
            float c = 0.0f, p = 0.0f;
            for (int w = 0; w < kWaves; ++w) { c += r0[w]; p += r1[w]; }
            float* slot = wsf + oPartials + ((size_t)b * kStreamPerB + slice) * 2;
            cstoref(&slot[0], c);
            cstoref(&slot[1], p);
        }
    }

    // ---- publish & elect (cheap): vmcnt-drain + relaxed fetch_add ----
    __syncthreads();   // each wave drains its outstanding (sc) stores
    if (tid == 0) {
        asm volatile("s_waitcnt vmcnt(0)" ::: "memory");
        unsigned old = __hip_atomic_fetch_add(&ws[oCnt + b], 1u,
                                              __ATOMIC_RELAXED,
                                              __HIP_MEMORY_SCOPE_AGENT);
        sh_last = (old == (unsigned)(kPerB - 1));
    }
    __syncthreads();
    if (!sh_last) return;

    // ================ finisher: radix select for batch b ================
    for (int i = tid; i < 2 * kWaves * 256; i += kTpb)
        ((unsigned*)whist)[i] = 0u;
    __syncthreads();

    unsigned vreg[kVPer];
    float mcnt = 0.0f, msum = 0.0f;
    #pragma unroll
    for (int it = 0; it < kVPer; ++it) {
        const int j = tid + it * kTpb;
        unsigned v = kSentinel;
        if (j < kNumNeg) v = cload(&ws[oGvals + b * kNumNeg + j]);
        vreg[it] = v;
        if (v != kSentinel) {
            mcnt += 1.0f;
            msum += __uint_as_float(v);
            atomicAdd(&whist[0][wave][v >> 24], 1u);  // v>=0 → bucket <128
        }
    }
    float c = 0.0f, p = 0.0f;
    if (tid < kStreamPerB) {
        const float* slot = wsf + oPartials + ((size_t)b * kStreamPerB + tid) * 2;
        c = cloadf(&slot[0]); p = cloadf(&slot[1]);
    }
    #pragma unroll
    for (int off = 32; off > 0; off >>= 1) {
        mcnt += __shfl_down(mcnt, off);
        msum += __shfl_down(msum, off);
        c    += __shfl_down(c, off);
        p    += __shfl_down(p, off);
    }
    if (lane == 0) { r0[wave] = mcnt; r1[wave] = msum; r2[wave] = c; r3[wave] = p; }
    __syncthreads();
    float my_loss = 0.0f;              // only thread 0's value used
    if (tid == 0) {
        float a0 = 0, a1 = 0, a2 = 0, a3 = 0;
        for (int w = 0; w < kWaves; ++w) { a0 += r0[w]; a1 += r1[w]; a2 += r2[w]; a3 += r3[w]; }
        sh_np = a2; sh_ps = a3;
        const int num_pos = (int)a2;
        const int m = (int)a0;
        const int k = (num_pos > 0) ? min(kRatio * num_pos, kNumNeg) : kNumHard;
        if (k >= m) {
            my_loss = (a3 + a1) / fmaxf(a2, 1.0f);
            sh_done = 1;
        } else {
            sh_done = 0;
            sh_krem = (unsigned)k;
            sh_prefix = 0u;
        }
    }
    __syncthreads();

    if (!sh_done) {
        #pragma unroll
        for (int pass = 0; pass < 4; ++pass) {
            const int shift = 24 - 8 * pass;
            if (pass > 0) {
                const unsigned pmask = 0xFFFFFFFFu << (shift + 8);
                const unsigned pval = sh_prefix;
                #pragma unroll
                for (int it = 0; it < kVPer; ++it) {
                    unsigned v = vreg[it];
                    if (v != kSentinel && (v & pmask) == pval)
                        atomicAdd(&whist[pass & 1][wave][(v >> shift) & 255u], 1u);
                }
                __syncthreads();
            }
            if (wave == 0) {
                const int binbase = 252 - 4 * lane;
                unsigned v0 = 0, v1 = 0, v2 = 0, v3 = 0;
                #pragma unroll
                for (int w = 0; w < kWaves; ++w) {
                    uint4 q = *(const uint4*)&whist[pass & 1][w][binbase];
                    v0 += q.x; v1 += q.y; v2 += q.z; v3 += q.w;
                }
                const unsigned d0 = v3, d1 = v2, d2 = v1, d3 = v0;
                const unsigned p0 = d0, p1 = p0 + d1, p2 = p1 + d2, p3 = p2 + d3;
                unsigned acc = p3;
                #pragma unroll
                for (int off = 1; off < 64; off <<= 1) {
                    unsigned y = __shfl_up(acc, off);
                    if (lane >= off) acc += y;
                }
                const unsigned excl = acc - p3;       // sfx of bin binbase+4
                const unsigned krem = sh_krem;
                const unsigned s0 = excl + p0, s1 = excl + p1,
                               s2 = excl + p2, s3 = excl + p3;
                if (s0 >= krem && excl < krem) {
                    sh_krem = krem - (s0 - d0);
                    sh_prefix |= (unsigned)(binbase + 3) << shift;
                } else if (s1 >= krem && s0 < krem) {
                    sh_krem = krem - (s1 - d1);
                    sh_prefix |= (unsigned)(binbase + 2) << shift;
                } else if (s2 >= krem && s1 < krem) {
                    sh_krem = krem - (s2 - d2);
                    sh_prefix |= (unsigned)(binbase + 1) << shift;
                } else if (s3 >= krem && s2 < krem) {
                    sh_krem = krem - (s3 - d3);
                    sh_prefix |= (unsigned)(binbase + 0) << shift;
                }
            } else {
                for (int i = tid - 64; i < kWaves * 256; i += kTpb - 64)
                    ((unsigned*)whist[(pass + 1) & 1])[i] = 0u;
            }
            __syncthreads();
        }

        const unsigned tbits = sh_prefix;
        float gsum = 0.0f;
        #pragma unroll
        for (int it = 0; it < kVPer; ++it) {
            unsigned v = vreg[it];
            if (v != kSentinel && v > tbits) gsum += __uint_as_float(v);
        }
        #pragma unroll
        for (int off = 32; off > 0; off >>= 1) gsum += __shfl_down(gsum, off);
        if (lane == 0) red[wave] = gsum;
        __syncthreads();
        if (tid == 0) {
            float sum_gt = 0.0f;
            for (int w = 0; w < kWaves; ++w) sum_gt += red[w];
            const float tval = __uint_as_float(tbits);
            const float neg_sum = sum_gt + (float)sh_krem * tval;
            my_loss = (sh_ps + neg_sum) / fmaxf(sh_np, 1.0f);
        }
    }

    // ---- finalize: 8th batch-finisher computes the mean (fixed order) ----
    if (tid == 0) {
        cstoref(&wsf[oBatchLoss + b], my_loss);
        asm volatile("s_waitcnt vmcnt(0)" ::: "memory");
        unsigned old = __hip_atomic_fetch_add(&ws[oGCnt], 1u, __ATOMIC_RELAXED,
                                              __HIP_MEMORY_SCOPE_AGENT);
        if (old == (unsigned)(kB - 1)) {
            float s = 0.0f;
            for (int i = 0; i < kB; ++i)
                s += cloadf(&wsf[oBatchLoss + i]);
            out[0] = s / (float)kB;
        }
    }
}

} // namespace

extern "C" void kernel_launch(void* const* d_in, const int* in_sizes, int n_in,
                              void* d_out, int out_size, void* d_ws, size_t ws_size,
                              hipStream_t stream) {
    const float* pred   = (const float*)d_in[0];
    const float* target = (const float*)d_in[1];
    const float* mask   = (const float*)d_in[2];
    const int*   negidx = (const int*)d_in[3];
    unsigned* ws = (unsigned*)d_ws;
    float* out = (float*)d_out;

    // zero the 9 counters (36 B) each call — handshake is re-entrant
    hipMemsetAsync((char*)d_ws + oCnt * 4, 0, (oGCnt - oCnt + 1) * 4, stream);
    fused_kernel<<<dim3(kGrid), dim3(kTpb), 0, stream>>>(pred, target, mask,
                                                         negidx, ws, out);
}